// Round 5
// baseline (361.935 us; speedup 1.0000x reference)
//
#include <hip/hip_runtime.h>

typedef __bf16 bf16_t;
typedef __bf16 bf16x8 __attribute__((ext_vector_type(8)));
typedef __bf16 bf16x4 __attribute__((ext_vector_type(4)));
typedef float  f32x4  __attribute__((ext_vector_type(4)));
typedef short  s16x4  __attribute__((ext_vector_type(4)));

#define DEV __device__ __forceinline__

// ---- constants ----
#define BB 8
#define SS 2048
#define HH 768
#define NHH 12
#define HD 64
#define NX (BB*SS*HH)      // 12582912
#define NW (HH*HH)         // 589824

// async global->LDS, 16B per lane; LDS dest must be wave-uniform base + lane*16
DEV void gl_lds16(const void* g, void* s) {
  __builtin_amdgcn_global_load_lds(
      (__attribute__((address_space(1))) void*)(void*)g,
      (__attribute__((address_space(3))) void*)s, 16, 0, 0);
}

DEV int swz4(int r) { return (r ^ (r >> 2)) & 3; }   // 4-chunk (64B) rows

DEV f32x4 mfma32(bf16x8 a, bf16x8 b, f32x4 c) {
  return __builtin_amdgcn_mfma_f32_16x16x32_bf16(a, b, c, 0, 0, 0);
}

// ============ kernel 1: fp32 -> bf16 conversion (X, Wq, Wk, Wv) ============
__global__ __launch_bounds__(256) void cvt_kernel(
    const float* __restrict__ X, const float* __restrict__ Wq,
    const float* __restrict__ Wk, const float* __restrict__ Wv,
    bf16_t* __restrict__ Xb, bf16_t* __restrict__ Wb) {
  int idx = (blockIdx.x * 256 + threadIdx.x) * 4;
  const float* src;
  bf16_t* dst;
  if (idx < NX) { src = X + idx; dst = Xb + idx; }
  else {
    int j = idx - NX;
    int w = j / NW;
    int jj = j - w * NW;
    src = (w == 0 ? Wq : (w == 1 ? Wk : Wv)) + jj;
    dst = Wb + j;
  }
  float4 v = *(const float4*)src;
  bf16x4 o;
  o[0] = (bf16_t)v.x; o[1] = (bf16_t)v.y; o[2] = (bf16_t)v.z; o[3] = (bf16_t)v.w;
  *(bf16x4*)dst = o;
}

// ============ kernel 2: fused QKV projection GEMM (double-buffered pipeline) ============
// z=0 -> Q [b][h][s][d] PRE-SCALED by 0.125*log2(e), z=1 -> K, z=2 -> V^T [b][h][d][s]
__global__ __launch_bounds__(256) void qkv_gemm(
    const bf16_t* __restrict__ Xb, const bf16_t* __restrict__ Wb,
    const float* __restrict__ bq, const float* __restrict__ bk,
    const float* __restrict__ bv,
    bf16_t* __restrict__ Q, bf16_t* __restrict__ K, bf16_t* __restrict__ VT) {
  __shared__ alignas(16) bf16_t ldsA[2][128 * 32];
  __shared__ alignas(16) bf16_t ldsB[2][128 * 32];

  const int t = threadIdx.x;
  const int w = t >> 6, l = t & 63, lr = l & 15, lq = l >> 4;
  const int wr = w >> 1, wc = w & 1;
  const int m0 = blockIdx.y * 128, n0 = blockIdx.x * 128;
  const int z = blockIdx.z;
  const bf16_t* W = Wb + z * NW;
  const float* bias = (z == 0) ? bq : (z == 1) ? bk : bv;
  // Q carries the softmax scale 0.125 and the exp2 conversion log2(e):
  const float osc = (z == 0) ? 0.1803368801f : 1.0f;

  const int sl0 = t, sl1 = t + 256;
  const int ra0 = sl0 >> 2, qa0 = (sl0 & 3) ^ swz4(ra0);
  const int ra1 = sl1 >> 2, qa1 = (sl1 & 3) ^ swz4(ra1);
  const bf16_t* A0 = Xb + (m0 + ra0) * HH + qa0 * 8;
  const bf16_t* A1 = Xb + (m0 + ra1) * HH + qa1 * 8;
  const bf16_t* B0 = W + (n0 + ra0) * HH + qa0 * 8;
  const bf16_t* B1 = W + (n0 + ra1) * HH + qa1 * 8;

  f32x4 acc[4][4] = {};

  int aoff[4], boff[4];
#pragma unroll
  for (int i = 0; i < 4; ++i) {
    int Ra = wr * 64 + i * 16 + lr;
    aoff[i] = (Ra * 4 + (lq ^ swz4(Ra))) * 8;
    int Rb = wc * 64 + i * 16 + lr;
    boff[i] = (Rb * 4 + (lq ^ swz4(Rb))) * 8;
  }

  auto stage = [&](int buf, int kt) {
    int ko = kt * 32;
    gl_lds16(A0 + ko, ldsA[buf] + sl0 * 8);
    gl_lds16(A1 + ko, ldsA[buf] + sl1 * 8);
    gl_lds16(B0 + ko, ldsB[buf] + sl0 * 8);
    gl_lds16(B1 + ko, ldsB[buf] + sl1 * 8);
  };

  auto compute = [&](const int buf) {
    bf16x8 a[4], bb[4];
#pragma unroll
    for (int i = 0; i < 4; ++i) a[i] = *(const bf16x8*)(ldsA[buf] + aoff[i]);
#pragma unroll
    for (int j = 0; j < 4; ++j) bb[j] = *(const bf16x8*)(ldsB[buf] + boff[j]);
#pragma unroll
    for (int i = 0; i < 4; ++i)
#pragma unroll
      for (int j = 0; j < 4; ++j)
        acc[i][j] = __builtin_amdgcn_mfma_f32_16x16x32_bf16(a[i], bb[j], acc[i][j], 0, 0, 0);
  };

  stage(0, 0);
  __syncthreads();     // tile0 drained
  stage(1, 1);         // in flight under compute(0)
  compute(0);
  for (int kt = 1; kt < 23; kt += 2) {
    __syncthreads();   // drains stage(buf1,kt); all waves done with buf0
    stage(0, kt + 1);
    compute(1);
    __syncthreads();   // drains stage(buf0,kt+1); all waves done with buf1
    stage(1, kt + 2);
    compute(0);
  }
  __syncthreads();     // drains stage(buf1,23)
  compute(1);

  const int mb = m0 + wr * 64, nb = n0 + wc * 64;
#pragma unroll
  for (int j = 0; j < 4; ++j) {
    int n = nb + j * 16 + lr;
    int h = n >> 6, d = n & 63;
    float bbias = bias[n];
#pragma unroll
    for (int i = 0; i < 4; ++i) {
      int mrow = mb + i * 16 + lq * 4;
      int b = mrow >> 11, s = mrow & 2047;
      if (z == 2) {
        bf16x4 pk;
#pragma unroll
        for (int r = 0; r < 4; ++r) pk[r] = (bf16_t)(acc[i][j][r] + bbias);
        *(bf16x4*)(VT + ((size_t)(b * NHH + h) * HD + d) * SS + s) = pk;
      } else {
        bf16_t* O = (z == 0) ? Q : K;
#pragma unroll
        for (int r = 0; r < 4; ++r)
          O[((size_t)(b * NHH + h) * SS + s + r) * HD + d] = (bf16_t)((acc[i][j][r] + bbias) * osc);
      }
    }
  }
}

// ============ kernel 3: flash attention ============
// Round-5: ALL MFMA now 16x16x32.  Round-4 counters proved the legacy
// 16x16x16_1k shape is HALF-RATE on gfx950 (MfmaUtil 48.8% only fits if
// x16 occupies the pipe like x32: 931~988 cyc/wave-kt), so PV (32 instr)
// and Lsum (8) wasted ~45% of MFMA-pipe time.  P's register layout
// (lane=k-quad) doesn't match the x32 B-frag (lane=k-octet), so P takes a
// per-wave LDS round-trip (2 KB/wave, NO barrier: DS is in-order per wave):
// 8 ds_write_b64 + 4 ds_read_b128 per kt buys PV 32->16, Lsum 8->4.
// New MFMA/kt/wave: QK 8 + Lsum 4 + PV 16 = 28 x32 (543 cyc vs 988).
// LDS 32+8 = 40 KB -> still exactly 4 blocks/CU at launch_bounds(256,4).
__global__ __launch_bounds__(256, 4) void flash_kernel(
    const bf16_t* __restrict__ Q, const bf16_t* __restrict__ K,
    const bf16_t* __restrict__ VT, const float* __restrict__ mask,
    float* __restrict__ out) {
  // [buf][0] = K tile (64x64), [buf][1] = V^T tile (64x64).  32768 B.
  __shared__ alignas(16) bf16_t ldsKV[2][2][64 * 64];
  // per-wave P scratch: 32 q-rows x 32 kv x bf16 = 2 KB/wave.
  __shared__ alignas(16) bf16_t ldsP[4][32 * 32];

  const int t = threadIdx.x;
  const int w = t >> 6, l = t & 63, lr = l & 15, lq = l >> 4;
  const int rs7 = lr & 7, rs3 = lr & 3;
  const int bh = blockIdx.x % 96, b = bh / NHH, h = bh - b * NHH;
  const int s0 = (blockIdx.x / 96) * 128;
  const bf16_t* Qb = Q + ((size_t)bh * SS + s0) * HD;
  const bf16_t* Kb = K + (size_t)bh * SS * HD;
  const bf16_t* Vb = VT + (size_t)bh * HD * SS;
  const float* mb = mask + b * SS;

  // ---- stage Q (128x64 = 16 KB) into the buf0 region, 8-chunk xor swizzle ----
  bf16_t* qs = &ldsKV[0][0][0];
#pragma unroll
  for (int i = 0; i < 4; ++i) {
    int sl = t + i * 256;
    int r = sl >> 3, q = (sl & 7) ^ (r & 7);
    gl_lds16(Qb + r * HD + q * 8, qs + sl * 8);
  }
  __syncthreads();   // Q staged

  bf16x8 aq0[2], aq1[2];
#pragma unroll
  for (int qi = 0; qi < 2; ++qi) {
    int Rq = w * 32 + qi * 16 + lr;
    aq0[qi] = *(const bf16x8*)(qs + (Rq * 8 + (lq ^ (Rq & 7))) * 8);
    aq1[qi] = *(const bf16x8*)(qs + (Rq * 8 + ((lq + 4) ^ (Rq & 7))) * 8);
  }
  __syncthreads();   // all waves hold Q in registers; buf0 region reusable

  const int c0 = t, c1 = t + 256;
  const int cr0 = c0 >> 3, cq0 = (c0 & 7) ^ (cr0 & 7);
  const int cr1 = c1 >> 3, cq1 = (c1 & 7) ^ (cr1 & 7);

  auto stage = [&](int buf, int kt) {
    const bf16_t* ks = Kb + kt * 64 * HD;
    gl_lds16(ks + cr0 * HD + cq0 * 8, ldsKV[buf][0] + c0 * 8);
    gl_lds16(ks + cr1 * HD + cq1 * 8, ldsKV[buf][0] + c1 * 8);
    gl_lds16(Vb + cr0 * SS + kt * 64 + cq0 * 8, ldsKV[buf][1] + c0 * 8);
    gl_lds16(Vb + cr1 * SS + kt * 64 + cq1 * 8, ldsKV[buf][1] + c1 * 8);
  };

  // ---- per-lane LDS byte bases (loop-invariant; reads = base + imm) ----
  // K: row Rk = j*16+lr, chunk lq / lq+4 (xor rs7), + j*2048
  const char* LB = (const char*)&ldsKV[0][0][0];
  const int kb0 = lr * 128 + ((lq ^ rs7) * 16);
  const int kb1 = lr * 128 + (((lq + 4) ^ rs7) * 16);
  // V (x32 A-frag): row d = dt*16+lr, kv-octet g*4+lq (xor rs7), + dt*2048
  int vg[2];
#pragma unroll
  for (int g = 0; g < 2; ++g) vg[g] = lr * 128 + (((g * 4 + lq) ^ rs7) * 16);
  // P scratch: row R = qi*16+lr (64 B/row, 4 chunks of 8 kv, xor rs3 swizzle)
  // write (per jj,qi): kvloc = jj*16 + lq*4 + r -> chunk jj*2+(lq>>1), half lq&1
  // read  (per qi):    kv-octet lq -> chunk lq
  char* PWb = (char*)&ldsP[0][0] + w * 2048 + lr * 64 + (lq & 1) * 8;
  char* PW0 = PWb + ((((lq >> 1)) ^ rs3) * 16);
  char* PW1 = PWb + (((2 + (lq >> 1)) ^ rs3) * 16);
  const char* PR = (const char*)&ldsP[0][0] + w * 2048 + lr * 64 + ((lq ^ rs3) * 16);

  f32x4 O[2][4] = {};
  f32x4 Lacc[2] = {};
  bf16x8 ones8;
#pragma unroll
  for (int r = 0; r < 8; ++r) ones8[r] = (bf16_t)1.0f;

  const float L2E = 1.44269504f;

  // BUFB: byte offset of the double-buffer half (0 or 16384) — literal at call sites.
  auto compute = [&](const int BUFB, int kt) {
    const char* Kbase = LB + BUFB;
    const char* Vbase = LB + BUFB + 8192;

#pragma unroll
    for (int g = 0; g < 2; ++g) {
      // ---- QK^T + exp2 for kv-group g (32 kv), P -> per-wave LDS ----
#pragma unroll
      for (int jj = 0; jj < 2; ++jj) {
        const int j = g * 2 + jj;
        bf16x8 k0 = *(const bf16x8*)(Kbase + kb0 + j * 2048);
        bf16x8 k1 = *(const bf16x8*)(Kbase + kb1 + j * 2048);
        f32x4 mvv = *(const f32x4*)(mb + kt * 64 + j * 16 + lq * 4);
        f32x4 marg = mvv * L2E;
#pragma unroll
        for (int qi = 0; qi < 2; ++qi) {
          f32x4 st = mfma32(k0, aq0[qi], marg);
          st = mfma32(k1, aq1[qi], st);
          bf16x4 p4;
#pragma unroll
          for (int r = 0; r < 4; ++r)
            p4[r] = (bf16_t)__builtin_amdgcn_exp2f(st[r]);
          *(bf16x4*)((jj == 0 ? PW0 : PW1) + qi * 1024) = p4;
        }
      }
      // ---- read P back as x32 B-frags (RAW within wave; DS in-order) ----
      bf16x8 p0 = *(const bf16x8*)(PR);
      bf16x8 p1 = *(const bf16x8*)(PR + 1024);
      // ---- l += 1^T . P^T  (K=32) ----
      Lacc[0] = mfma32(ones8, p0, Lacc[0]);
      Lacc[1] = mfma32(ones8, p1, Lacc[1]);
      // ---- O^T += V^T . P^T  (K=32) ----
#pragma unroll
      for (int dt = 0; dt < 4; ++dt) {
        bf16x8 av = *(const bf16x8*)(Vbase + vg[g] + dt * 2048);
        O[0][dt] = mfma32(av, p0, O[0][dt]);
        O[1][dt] = mfma32(av, p1, O[1][dt]);
      }
    }
  };

  stage(0, 0);
  __syncthreads();   // tile0 drained
  stage(1, 1);       // in flight under compute(0)
  compute(0, 0);
  for (int kt = 1; kt < 31; kt += 2) {
    __syncthreads();               // drains stage of buf1(kt); all waves done with buf0
    stage(0, kt + 1);
    compute(16384, kt);
    __syncthreads();               // drains stage of buf0(kt+1); all done with buf1
    stage(1, kt + 2);
    compute(0, kt + 1);
  }
  __syncthreads();
  compute(16384, 31);

  // ---- epilogue: inv from MFMA row-sum (no shuffles) ----
#pragma unroll
  for (int qi = 0; qi < 2; ++qi) {
    float inv = 1.0f / Lacc[qi][0];
    int srow = s0 + w * 32 + qi * 16 + lr;
    float* op = out + ((size_t)b * SS + srow) * HH + h * HD;
#pragma unroll
    for (int dt = 0; dt < 4; ++dt) {
      f32x4 o = O[qi][dt];
      o *= inv;
      *(f32x4*)(op + dt * 16 + lq * 4) = o;
    }
  }
}

// ============ launcher ============
extern "C" void kernel_launch(void* const* d_in, const int* in_sizes, int n_in,
                              void* d_out, int out_size, void* d_ws, size_t ws_size,
                              hipStream_t stream) {
  const float* X    = (const float*)d_in[0];
  const float* mask = (const float*)d_in[1];
  const float* Wq   = (const float*)d_in[2];
  const float* bq   = (const float*)d_in[3];
  const float* Wk   = (const float*)d_in[4];
  const float* bk   = (const float*)d_in[5];
  const float* Wv   = (const float*)d_in[6];
  const float* bv   = (const float*)d_in[7];
  float* out = (float*)d_out;

  char* ws = (char*)d_ws;
  bf16_t* Xb = (bf16_t*)(ws);                        // 25165824 B
  bf16_t* Wb = (bf16_t*)(ws + 25165824);             //  3538944 B
  bf16_t* Qb = (bf16_t*)(ws + 28704768);             // 25165824 B
  bf16_t* Kb = (bf16_t*)(ws + 53870592);             // 25165824 B
  bf16_t* VT = (bf16_t*)(ws + 79036416);             // 25165824 B

  cvt_kernel<<<14016, 256, 0, stream>>>(X, Wq, Wk, Wv, Xb, Wb);
  qkv_gemm<<<dim3(6, 128, 3), 256, 0, stream>>>(Xb, Wb, bq, bk, bv, Qb, Kb, VT);
  flash_kernel<<<1536, 256, 0, stream>>>(Qb, Kb, VT, mask, out);
}

// Round 7
// 324.674 us; speedup vs baseline: 1.1148x; 1.1148x over previous
//
#include <hip/hip_runtime.h>

typedef __bf16 bf16_t;
typedef __bf16 bf16x8 __attribute__((ext_vector_type(8)));
typedef __bf16 bf16x4 __attribute__((ext_vector_type(4)));
typedef float  f32x4  __attribute__((ext_vector_type(4)));
typedef short  s16x4  __attribute__((ext_vector_type(4)));

#define DEV __device__ __forceinline__

// ---- constants ----
#define BB 8
#define SS 2048
#define HH 768
#define NHH 12
#define HD 64
#define NX (BB*SS*HH)      // 12582912
#define NW (HH*HH)         // 589824

// async global->LDS, 16B per lane; LDS dest must be wave-uniform base + lane*16
DEV void gl_lds16(const void* g, void* s) {
  __builtin_amdgcn_global_load_lds(
      (__attribute__((address_space(1))) void*)(void*)g,
      (__attribute__((address_space(3))) void*)s, 16, 0, 0);
}

DEV int swz4(int r) { return (r ^ (r >> 2)) & 3; }   // 4-chunk (64B) rows

DEV f32x4 mfma32(bf16x8 a, bf16x8 b, f32x4 c) {
  return __builtin_amdgcn_mfma_f32_16x16x32_bf16(a, b, c, 0, 0, 0);
}

// ============ kernel 1: fp32 -> bf16 conversion (X, Wq, Wk, Wv) ============
__global__ __launch_bounds__(256) void cvt_kernel(
    const float* __restrict__ X, const float* __restrict__ Wq,
    const float* __restrict__ Wk, const float* __restrict__ Wv,
    bf16_t* __restrict__ Xb, bf16_t* __restrict__ Wb) {
  int idx = (blockIdx.x * 256 + threadIdx.x) * 4;
  const float* src;
  bf16_t* dst;
  if (idx < NX) { src = X + idx; dst = Xb + idx; }
  else {
    int j = idx - NX;
    int w = j / NW;
    int jj = j - w * NW;
    src = (w == 0 ? Wq : (w == 1 ? Wk : Wv)) + jj;
    dst = Wb + j;
  }
  float4 v = *(const float4*)src;
  bf16x4 o;
  o[0] = (bf16_t)v.x; o[1] = (bf16_t)v.y; o[2] = (bf16_t)v.z; o[3] = (bf16_t)v.w;
  *(bf16x4*)dst = o;
}

// ============ kernel 2: fused QKV projection GEMM (double-buffered pipeline) ============
// z=0 -> Q [b][h][s][d] PRE-SCALED by 0.125*log2(e), z=1 -> K
// z=2 -> V^T [b][h][d][s] with a PERMUTED kv order inside every 64-block:
//   stored = (i>>1)*32 + lq*8 + (i&1)*4 + r   for original sb = i*16+lq*4+r.
// This makes flash's PV x32 B-frag (k-octets) equal a register concat of the
// QK output quads (lane-local), so P needs no LDS round-trip / shuffles.
__global__ __launch_bounds__(256) void qkv_gemm(
    const bf16_t* __restrict__ Xb, const bf16_t* __restrict__ Wb,
    const float* __restrict__ bq, const float* __restrict__ bk,
    const float* __restrict__ bv,
    bf16_t* __restrict__ Q, bf16_t* __restrict__ K, bf16_t* __restrict__ VT) {
  __shared__ alignas(16) bf16_t ldsA[2][128 * 32];
  __shared__ alignas(16) bf16_t ldsB[2][128 * 32];

  const int t = threadIdx.x;
  const int w = t >> 6, l = t & 63, lr = l & 15, lq = l >> 4;
  const int wr = w >> 1, wc = w & 1;
  const int m0 = blockIdx.y * 128, n0 = blockIdx.x * 128;
  const int z = blockIdx.z;
  const bf16_t* W = Wb + z * NW;
  const float* bias = (z == 0) ? bq : (z == 1) ? bk : bv;
  // Q carries the softmax scale 0.125 and the exp2 conversion log2(e):
  const float osc = (z == 0) ? 0.1803368801f : 1.0f;

  const int sl0 = t, sl1 = t + 256;
  const int ra0 = sl0 >> 2, qa0 = (sl0 & 3) ^ swz4(ra0);
  const int ra1 = sl1 >> 2, qa1 = (sl1 & 3) ^ swz4(ra1);
  const bf16_t* A0 = Xb + (m0 + ra0) * HH + qa0 * 8;
  const bf16_t* A1 = Xb + (m0 + ra1) * HH + qa1 * 8;
  const bf16_t* B0 = W + (n0 + ra0) * HH + qa0 * 8;
  const bf16_t* B1 = W + (n0 + ra1) * HH + qa1 * 8;

  f32x4 acc[4][4] = {};

  int aoff[4], boff[4];
#pragma unroll
  for (int i = 0; i < 4; ++i) {
    int Ra = wr * 64 + i * 16 + lr;
    aoff[i] = (Ra * 4 + (lq ^ swz4(Ra))) * 8;
    int Rb = wc * 64 + i * 16 + lr;
    boff[i] = (Rb * 4 + (lq ^ swz4(Rb))) * 8;
  }

  auto stage = [&](int buf, int kt) {
    int ko = kt * 32;
    gl_lds16(A0 + ko, ldsA[buf] + sl0 * 8);
    gl_lds16(A1 + ko, ldsA[buf] + sl1 * 8);
    gl_lds16(B0 + ko, ldsB[buf] + sl0 * 8);
    gl_lds16(B1 + ko, ldsB[buf] + sl1 * 8);
  };

  auto compute = [&](const int buf) {
    bf16x8 a[4], bb[4];
#pragma unroll
    for (int i = 0; i < 4; ++i) a[i] = *(const bf16x8*)(ldsA[buf] + aoff[i]);
#pragma unroll
    for (int j = 0; j < 4; ++j) bb[j] = *(const bf16x8*)(ldsB[buf] + boff[j]);
#pragma unroll
    for (int i = 0; i < 4; ++i)
#pragma unroll
      for (int j = 0; j < 4; ++j)
        acc[i][j] = __builtin_amdgcn_mfma_f32_16x16x32_bf16(a[i], bb[j], acc[i][j], 0, 0, 0);
  };

  stage(0, 0);
  __syncthreads();     // tile0 drained
  stage(1, 1);         // in flight under compute(0)
  compute(0);
  for (int kt = 1; kt < 23; kt += 2) {
    __syncthreads();   // drains stage(buf1,kt); all waves done with buf0
    stage(0, kt + 1);
    compute(1);
    __syncthreads();   // drains stage(buf0,kt+1); all waves done with buf1
    stage(1, kt + 2);
    compute(0);
  }
  __syncthreads();     // drains stage(buf1,23)
  compute(1);

  const int mb = m0 + wr * 64, nb = n0 + wc * 64;
#pragma unroll
  for (int j = 0; j < 4; ++j) {
    int n = nb + j * 16 + lr;
    int h = n >> 6, d = n & 63;
    float bbias = bias[n];
#pragma unroll
    for (int i = 0; i < 4; ++i) {
      int mrow = mb + i * 16 + lq * 4;
      int b = mrow >> 11, s = mrow & 2047;
      if (z == 2) {
        bf16x4 pk;
#pragma unroll
        for (int r = 0; r < 4; ++r) pk[r] = (bf16_t)(acc[i][j][r] + bbias);
        // permuted kv order within the 64-block (see header comment)
        int sperm = (s & ~63) + ((i >> 1) << 5) + (lq << 3) + ((i & 1) << 2);
        *(bf16x4*)(VT + ((size_t)(b * NHH + h) * HD + d) * SS + sperm) = pk;
      } else {
        bf16_t* O = (z == 0) ? Q : K;
#pragma unroll
        for (int r = 0; r < 4; ++r)
          O[((size_t)(b * NHH + h) * SS + s + r) * HD + d] = (bf16_t)((acc[i][j][r] + bbias) * osc);
      }
    }
  }
}

// ============ kernel 3: flash attention (all-x32 MFMA, zero-cost P re-layout) ============
// Round-6: keep the x32 PV (round-5 proved x16 is half-rate: MFMA-busy
// 79us -> 49us) but drop the P LDS round-trip that killed round-5 (serial
// write->read chain + 4-8 way bank-conflict floor; conflicts 1.26e7->2.2e7).
// Instead V^T is stored (by qkv_gemm) in the permuted kv order
//   stored = (j>>1)*32 + lq*8 + (j&1)*4 + r,
// which makes the x32 PV B-frag octet for lane lq the register CONCAT of its
// QK output quads j=2gi, 2gi+1 -- lane-local, no LDS, no shuffles.  The V
// A-frag chunk index (gi*4+lq) is unchanged.  MFMA/kt/wave: QK 16 + Lsum 4 +
// PV 16 = 36 x32.  LDS back to 32 KB; launch_bounds(256,4) -> 4 blocks/CU.
__global__ __launch_bounds__(256, 4) void flash_kernel(
    const bf16_t* __restrict__ Q, const bf16_t* __restrict__ K,
    const bf16_t* __restrict__ VT, const float* __restrict__ mask,
    float* __restrict__ out) {
  // [buf][0] = K tile (64x64), [buf][1] = V^T tile (64x64).  32768 B total.
  __shared__ alignas(16) bf16_t ldsKV[2][2][64 * 64];

  const int t = threadIdx.x;
  const int w = t >> 6, l = t & 63, lr = l & 15, lq = l >> 4;
  const int rs7 = lr & 7;
  const int bh = blockIdx.x % 96, b = bh / NHH, h = bh - b * NHH;
  const int s0 = (blockIdx.x / 96) * 128;
  const bf16_t* Qb = Q + ((size_t)bh * SS + s0) * HD;
  const bf16_t* Kb = K + (size_t)bh * SS * HD;
  const bf16_t* Vb = VT + (size_t)bh * HD * SS;
  const float* mb = mask + b * SS;

  // ---- stage Q (128x64 = 16 KB) into the buf0 region, 8-chunk xor swizzle ----
  bf16_t* qs = &ldsKV[0][0][0];
#pragma unroll
  for (int i = 0; i < 4; ++i) {
    int sl = t + i * 256;
    int r = sl >> 3, q = (sl & 7) ^ (r & 7);
    gl_lds16(Qb + r * HD + q * 8, qs + sl * 8);
  }
  __syncthreads();   // Q staged

  bf16x8 aq0[2], aq1[2];
#pragma unroll
  for (int qi = 0; qi < 2; ++qi) {
    int Rq = w * 32 + qi * 16 + lr;
    aq0[qi] = *(const bf16x8*)(qs + (Rq * 8 + (lq ^ (Rq & 7))) * 8);
    aq1[qi] = *(const bf16x8*)(qs + (Rq * 8 + ((lq + 4) ^ (Rq & 7))) * 8);
  }
  __syncthreads();   // all waves hold Q in registers; buf0 region reusable

  const int c0 = t, c1 = t + 256;
  const int cr0 = c0 >> 3, cq0 = (c0 & 7) ^ (cr0 & 7);
  const int cr1 = c1 >> 3, cq1 = (c1 & 7) ^ (cr1 & 7);

  auto stage = [&](int buf, int kt) {
    const bf16_t* ks = Kb + kt * 64 * HD;
    gl_lds16(ks + cr0 * HD + cq0 * 8, ldsKV[buf][0] + c0 * 8);
    gl_lds16(ks + cr1 * HD + cq1 * 8, ldsKV[buf][0] + c1 * 8);
    gl_lds16(Vb + cr0 * SS + kt * 64 + cq0 * 8, ldsKV[buf][1] + c0 * 8);
    gl_lds16(Vb + cr1 * SS + kt * 64 + cq1 * 8, ldsKV[buf][1] + c1 * 8);
  };

  // ---- per-lane LDS byte bases (loop-invariant; reads = base + imm) ----
  // K: row Rk = j*16+lr, chunk lq / lq+4 (xor rs7), + j*2048
  const char* LB = (const char*)&ldsKV[0][0][0];
  const int kb0 = lr * 128 + ((lq ^ rs7) * 16);
  const int kb1 = lr * 128 + (((lq + 4) ^ rs7) * 16);
  // V (x32 A-frag): row d = dt*16+lr, stored-octet chunk gi*4+lq (xor rs7)
  int vg[2];
#pragma unroll
  for (int g = 0; g < 2; ++g) vg[g] = lr * 128 + (((g * 4 + lq) ^ rs7) * 16);

  f32x4 O[2][4] = {};
  f32x4 Lacc[2] = {};
  bf16x8 ones8;
#pragma unroll
  for (int r = 0; r < 8; ++r) ones8[r] = (bf16_t)1.0f;

  const float L2E = 1.44269504f;

  // BUFB: byte offset of the double-buffer half (0 or 16384) — literal at call sites.
  auto compute = [&](const int BUFB, int kt) {
    const char* Kbase = LB + BUFB;
    const char* Vbase = LB + BUFB + 8192;

#pragma unroll
    for (int gi = 0; gi < 2; ++gi) {
      bf16x8 pf[2];   // per qi: x32 B-frag octet = concat of quads j=2gi, 2gi+1
#pragma unroll
      for (int jj = 0; jj < 2; ++jj) {
        const int j = gi * 2 + jj;
        bf16x8 k0 = *(const bf16x8*)(Kbase + kb0 + j * 2048);
        bf16x8 k1 = *(const bf16x8*)(Kbase + kb1 + j * 2048);
        f32x4 mvv = *(const f32x4*)(mb + kt * 64 + j * 16 + lq * 4);
        f32x4 marg = mvv * L2E;
#pragma unroll
        for (int qi = 0; qi < 2; ++qi) {
          f32x4 st = mfma32(k0, aq0[qi], marg);
          st = mfma32(k1, aq1[qi], st);
#pragma unroll
          for (int r = 0; r < 4; ++r)
            pf[qi][jj * 4 + r] = (bf16_t)__builtin_amdgcn_exp2f(st[r]);
        }
      }
      // ---- l += 1^T . P^T  (K=32, MFMA pipe) ----
      Lacc[0] = mfma32(ones8, pf[0], Lacc[0]);
      Lacc[1] = mfma32(ones8, pf[1], Lacc[1]);
      // ---- O^T += V^T . P^T  (K=32, V in permuted-stored order) ----
#pragma unroll
      for (int dt = 0; dt < 4; ++dt) {
        bf16x8 av = *(const bf16x8*)(Vbase + vg[gi] + dt * 2048);
        O[0][dt] = mfma32(av, pf[0], O[0][dt]);
        O[1][dt] = mfma32(av, pf[1], O[1][dt]);
      }
    }
  };

  stage(0, 0);
  __syncthreads();   // tile0 drained
  stage(1, 1);       // in flight under compute(0)
  compute(0, 0);
  for (int kt = 1; kt < 31; kt += 2) {
    __syncthreads();               // drains stage of buf1(kt); all waves done with buf0
    stage(0, kt + 1);
    compute(16384, kt);
    __syncthreads();               // drains stage of buf0(kt+1); all done with buf1
    stage(1, kt + 2);
    compute(0, kt + 1);
  }
  __syncthreads();
  compute(16384, 31);

  // ---- epilogue: inv from MFMA row-sum (no shuffles) ----
#pragma unroll
  for (int qi = 0; qi < 2; ++qi) {
    float inv = 1.0f / Lacc[qi][0];
    int srow = s0 + w * 32 + qi * 16 + lr;
    float* op = out + ((size_t)b * SS + srow) * HH + h * HD;
#pragma unroll
    for (int dt = 0; dt < 4; ++dt) {
      f32x4 o = O[qi][dt];
      o *= inv;
      *(f32x4*)(op + dt * 16 + lq * 4) = o;
    }
  }
}

// ============ launcher ============
extern "C" void kernel_launch(void* const* d_in, const int* in_sizes, int n_in,
                              void* d_out, int out_size, void* d_ws, size_t ws_size,
                              hipStream_t stream) {
  const float* X    = (const float*)d_in[0];
  const float* mask = (const float*)d_in[1];
  const float* Wq   = (const float*)d_in[2];
  const float* bq   = (const float*)d_in[3];
  const float* Wk   = (const float*)d_in[4];
  const float* bk   = (const float*)d_in[5];
  const float* Wv   = (const float*)d_in[6];
  const float* bv   = (const float*)d_in[7];
  float* out = (float*)d_out;

  char* ws = (char*)d_ws;
  bf16_t* Xb = (bf16_t*)(ws);                        // 25165824 B
  bf16_t* Wb = (bf16_t*)(ws + 25165824);             //  3538944 B
  bf16_t* Qb = (bf16_t*)(ws + 28704768);             // 25165824 B
  bf16_t* Kb = (bf16_t*)(ws + 53870592);             // 25165824 B
  bf16_t* VT = (bf16_t*)(ws + 79036416);             // 25165824 B

  cvt_kernel<<<14016, 256, 0, stream>>>(X, Wq, Wk, Wv, Xb, Wb);
  qkv_gemm<<<dim3(6, 128, 3), 256, 0, stream>>>(Xb, Wb, bq, bk, bv, Qb, Kb, VT);
  flash_kernel<<<1536, 256, 0, stream>>>(Qb, Kb, VT, mask, out);
}

// Round 8
// 313.293 us; speedup vs baseline: 1.1553x; 1.0363x over previous
//
#include <hip/hip_runtime.h>

typedef __bf16 bf16_t;
typedef __bf16 bf16x8 __attribute__((ext_vector_type(8)));
typedef __bf16 bf16x4 __attribute__((ext_vector_type(4)));
typedef float  f32x4  __attribute__((ext_vector_type(4)));
typedef short  s16x4  __attribute__((ext_vector_type(4)));

#define DEV __device__ __forceinline__

// ---- constants ----
#define BB 8
#define SS 2048
#define HH 768
#define NHH 12
#define HD 64
#define NX (BB*SS*HH)      // 12582912
#define NW (HH*HH)         // 589824

// async global->LDS, 16B per lane; LDS dest must be wave-uniform base + lane*16
DEV void gl_lds16(const void* g, void* s) {
  __builtin_amdgcn_global_load_lds(
      (__attribute__((address_space(1))) void*)(void*)g,
      (__attribute__((address_space(3))) void*)s, 16, 0, 0);
}

DEV int swz4(int r) { return (r ^ (r >> 2)) & 3; }   // 4-chunk (64B) rows

DEV f32x4 mfma32(bf16x8 a, bf16x8 b, f32x4 c) {
  return __builtin_amdgcn_mfma_f32_16x16x32_bf16(a, b, c, 0, 0, 0);
}

// ============ kernel 1: fp32 -> bf16 conversion (X, Wq, Wk, Wv) ============
__global__ __launch_bounds__(256) void cvt_kernel(
    const float* __restrict__ X, const float* __restrict__ Wq,
    const float* __restrict__ Wk, const float* __restrict__ Wv,
    bf16_t* __restrict__ Xb, bf16_t* __restrict__ Wb) {
  int idx = (blockIdx.x * 256 + threadIdx.x) * 4;
  const float* src;
  bf16_t* dst;
  if (idx < NX) { src = X + idx; dst = Xb + idx; }
  else {
    int j = idx - NX;
    int w = j / NW;
    int jj = j - w * NW;
    src = (w == 0 ? Wq : (w == 1 ? Wk : Wv)) + jj;
    dst = Wb + j;
  }
  float4 v = *(const float4*)src;
  bf16x4 o;
  o[0] = (bf16_t)v.x; o[1] = (bf16_t)v.y; o[2] = (bf16_t)v.z; o[3] = (bf16_t)v.w;
  *(bf16x4*)dst = o;
}

// ============ kernel 2: fused QKV projection GEMM (double-buffered pipeline) ============
// z=0 -> Q [b][h][s][d] PRE-SCALED by 0.125*log2(e), z=1 -> K
// z=2 -> V^T [b][h][d][s] with a PERMUTED kv order inside every 64-block:
//   stored = (i>>1)*32 + lq*8 + (i&1)*4 + r   for original sb = i*16+lq*4+r.
// This makes flash's PV x32 B-frag (k-octets) equal a register concat of the
// QK output quads (lane-local), so P needs no LDS round-trip / shuffles.
//
// Round-8: XCD-chunked block swizzle.  Old grid (6,128,3) put the 6 n-blocks
// sharing one 196KB A-panel on 6 DIFFERENT XCDs (consecutive ids, %8 round
// robin) -> every A-panel fetched 6x from L3/HBM (885 MB/dispatch raw tile
// demand vs ~100 MB unique).  Flat grid 2304 = 8*288: swz = (id&7)*288+id>>3
// gives each XCD 288 consecutive logical blocks = whole (m,z) groups, so an
// A-panel is loaded once into that XCD's L2 and reused by all 6 n-blocks
// (in-flight set ~1.2MB A + 1.2MB B < 4MB L2).  Bijective (2304%8==0).
__global__ __launch_bounds__(256) void qkv_gemm(
    const bf16_t* __restrict__ Xb, const bf16_t* __restrict__ Wb,
    const float* __restrict__ bq, const float* __restrict__ bk,
    const float* __restrict__ bv,
    bf16_t* __restrict__ Q, bf16_t* __restrict__ K, bf16_t* __restrict__ VT) {
  __shared__ alignas(16) bf16_t ldsA[2][128 * 32];
  __shared__ alignas(16) bf16_t ldsB[2][128 * 32];

  const int t = threadIdx.x;
  const int w = t >> 6, l = t & 63, lr = l & 15, lq = l >> 4;
  const int wr = w >> 1, wc = w & 1;

  const int id = blockIdx.x;
  const int swz = (id & 7) * 288 + (id >> 3);       // XCD-chunked remap
  const int z = swz / 768;
  const int rem = swz - z * 768;
  const int m0 = (rem / 6) * 128, n0 = (rem % 6) * 128;

  const bf16_t* W = Wb + z * NW;
  const float* bias = (z == 0) ? bq : (z == 1) ? bk : bv;
  // Q carries the softmax scale 0.125 and the exp2 conversion log2(e):
  const float osc = (z == 0) ? 0.1803368801f : 1.0f;

  const int sl0 = t, sl1 = t + 256;
  const int ra0 = sl0 >> 2, qa0 = (sl0 & 3) ^ swz4(ra0);
  const int ra1 = sl1 >> 2, qa1 = (sl1 & 3) ^ swz4(ra1);
  const bf16_t* A0 = Xb + (m0 + ra0) * HH + qa0 * 8;
  const bf16_t* A1 = Xb + (m0 + ra1) * HH + qa1 * 8;
  const bf16_t* B0 = W + (n0 + ra0) * HH + qa0 * 8;
  const bf16_t* B1 = W + (n0 + ra1) * HH + qa1 * 8;

  f32x4 acc[4][4] = {};

  int aoff[4], boff[4];
#pragma unroll
  for (int i = 0; i < 4; ++i) {
    int Ra = wr * 64 + i * 16 + lr;
    aoff[i] = (Ra * 4 + (lq ^ swz4(Ra))) * 8;
    int Rb = wc * 64 + i * 16 + lr;
    boff[i] = (Rb * 4 + (lq ^ swz4(Rb))) * 8;
  }

  auto stage = [&](int buf, int kt) {
    int ko = kt * 32;
    gl_lds16(A0 + ko, ldsA[buf] + sl0 * 8);
    gl_lds16(A1 + ko, ldsA[buf] + sl1 * 8);
    gl_lds16(B0 + ko, ldsB[buf] + sl0 * 8);
    gl_lds16(B1 + ko, ldsB[buf] + sl1 * 8);
  };

  auto compute = [&](const int buf) {
    bf16x8 a[4], bb[4];
#pragma unroll
    for (int i = 0; i < 4; ++i) a[i] = *(const bf16x8*)(ldsA[buf] + aoff[i]);
#pragma unroll
    for (int j = 0; j < 4; ++j) bb[j] = *(const bf16x8*)(ldsB[buf] + boff[j]);
#pragma unroll
    for (int i = 0; i < 4; ++i)
#pragma unroll
      for (int j = 0; j < 4; ++j)
        acc[i][j] = __builtin_amdgcn_mfma_f32_16x16x32_bf16(a[i], bb[j], acc[i][j], 0, 0, 0);
  };

  stage(0, 0);
  __syncthreads();     // tile0 drained
  stage(1, 1);         // in flight under compute(0)
  compute(0);
  for (int kt = 1; kt < 23; kt += 2) {
    __syncthreads();   // drains stage(buf1,kt); all waves done with buf0
    stage(0, kt + 1);
    compute(1);
    __syncthreads();   // drains stage(buf0,kt+1); all waves done with buf1
    stage(1, kt + 2);
    compute(0);
  }
  __syncthreads();     // drains stage(buf1,23)
  compute(1);

  const int mb = m0 + wr * 64, nb = n0 + wc * 64;
#pragma unroll
  for (int j = 0; j < 4; ++j) {
    int n = nb + j * 16 + lr;
    int h = n >> 6, d = n & 63;
    float bbias = bias[n];
#pragma unroll
    for (int i = 0; i < 4; ++i) {
      int mrow = mb + i * 16 + lq * 4;
      int b = mrow >> 11, s = mrow & 2047;
      if (z == 2) {
        bf16x4 pk;
#pragma unroll
        for (int r = 0; r < 4; ++r) pk[r] = (bf16_t)(acc[i][j][r] + bbias);
        // permuted kv order within the 64-block (see header comment)
        int sperm = (s & ~63) + ((i >> 1) << 5) + (lq << 3) + ((i & 1) << 2);
        *(bf16x4*)(VT + ((size_t)(b * NHH + h) * HD + d) * SS + sperm) = pk;
      } else {
        bf16_t* O = (z == 0) ? Q : K;
#pragma unroll
        for (int r = 0; r < 4; ++r)
          O[((size_t)(b * NHH + h) * SS + s + r) * HD + d] = (bf16_t)((acc[i][j][r] + bbias) * osc);
      }
    }
  }
}

// ============ kernel 3: flash attention (all-x32 MFMA, zero-cost P re-layout) ============
// Round-7 verified: x32-only MFMA + permuted-V register-concat P, bank
// conflicts = 0, FETCH = ideal 69 MB, both pipes ~36% (72% issue).  Unchanged.
__global__ __launch_bounds__(256, 4) void flash_kernel(
    const bf16_t* __restrict__ Q, const bf16_t* __restrict__ K,
    const bf16_t* __restrict__ VT, const float* __restrict__ mask,
    float* __restrict__ out) {
  // [buf][0] = K tile (64x64), [buf][1] = V^T tile (64x64).  32768 B total.
  __shared__ alignas(16) bf16_t ldsKV[2][2][64 * 64];

  const int t = threadIdx.x;
  const int w = t >> 6, l = t & 63, lr = l & 15, lq = l >> 4;
  const int rs7 = lr & 7;
  const int bh = blockIdx.x % 96, b = bh / NHH, h = bh - b * NHH;
  const int s0 = (blockIdx.x / 96) * 128;
  const bf16_t* Qb = Q + ((size_t)bh * SS + s0) * HD;
  const bf16_t* Kb = K + (size_t)bh * SS * HD;
  const bf16_t* Vb = VT + (size_t)bh * HD * SS;
  const float* mb = mask + b * SS;

  // ---- stage Q (128x64 = 16 KB) into the buf0 region, 8-chunk xor swizzle ----
  bf16_t* qs = &ldsKV[0][0][0];
#pragma unroll
  for (int i = 0; i < 4; ++i) {
    int sl = t + i * 256;
    int r = sl >> 3, q = (sl & 7) ^ (r & 7);
    gl_lds16(Qb + r * HD + q * 8, qs + sl * 8);
  }
  __syncthreads();   // Q staged

  bf16x8 aq0[2], aq1[2];
#pragma unroll
  for (int qi = 0; qi < 2; ++qi) {
    int Rq = w * 32 + qi * 16 + lr;
    aq0[qi] = *(const bf16x8*)(qs + (Rq * 8 + (lq ^ (Rq & 7))) * 8);
    aq1[qi] = *(const bf16x8*)(qs + (Rq * 8 + ((lq + 4) ^ (Rq & 7))) * 8);
  }
  __syncthreads();   // all waves hold Q in registers; buf0 region reusable

  const int c0 = t, c1 = t + 256;
  const int cr0 = c0 >> 3, cq0 = (c0 & 7) ^ (cr0 & 7);
  const int cr1 = c1 >> 3, cq1 = (c1 & 7) ^ (cr1 & 7);

  auto stage = [&](int buf, int kt) {
    const bf16_t* ks = Kb + kt * 64 * HD;
    gl_lds16(ks + cr0 * HD + cq0 * 8, ldsKV[buf][0] + c0 * 8);
    gl_lds16(ks + cr1 * HD + cq1 * 8, ldsKV[buf][0] + c1 * 8);
    gl_lds16(Vb + cr0 * SS + kt * 64 + cq0 * 8, ldsKV[buf][1] + c0 * 8);
    gl_lds16(Vb + cr1 * SS + kt * 64 + cq1 * 8, ldsKV[buf][1] + c1 * 8);
  };

  // ---- per-lane LDS byte bases (loop-invariant; reads = base + imm) ----
  // K: row Rk = j*16+lr, chunk lq / lq+4 (xor rs7), + j*2048
  const char* LB = (const char*)&ldsKV[0][0][0];
  const int kb0 = lr * 128 + ((lq ^ rs7) * 16);
  const int kb1 = lr * 128 + (((lq + 4) ^ rs7) * 16);
  // V (x32 A-frag): row d = dt*16+lr, stored-octet chunk gi*4+lq (xor rs7)
  int vg[2];
#pragma unroll
  for (int g = 0; g < 2; ++g) vg[g] = lr * 128 + (((g * 4 + lq) ^ rs7) * 16);

  f32x4 O[2][4] = {};
  f32x4 Lacc[2] = {};
  bf16x8 ones8;
#pragma unroll
  for (int r = 0; r < 8; ++r) ones8[r] = (bf16_t)1.0f;

  const float L2E = 1.44269504f;

  // BUFB: byte offset of the double-buffer half (0 or 16384) — literal at call sites.
  auto compute = [&](const int BUFB, int kt) {
    const char* Kbase = LB + BUFB;
    const char* Vbase = LB + BUFB + 8192;

#pragma unroll
    for (int gi = 0; gi < 2; ++gi) {
      bf16x8 pf[2];   // per qi: x32 B-frag octet = concat of quads j=2gi, 2gi+1
#pragma unroll
      for (int jj = 0; jj < 2; ++jj) {
        const int j = gi * 2 + jj;
        bf16x8 k0 = *(const bf16x8*)(Kbase + kb0 + j * 2048);
        bf16x8 k1 = *(const bf16x8*)(Kbase + kb1 + j * 2048);
        f32x4 mvv = *(const f32x4*)(mb + kt * 64 + j * 16 + lq * 4);
        f32x4 marg = mvv * L2E;
#pragma unroll
        for (int qi = 0; qi < 2; ++qi) {
          f32x4 st = mfma32(k0, aq0[qi], marg);
          st = mfma32(k1, aq1[qi], st);
#pragma unroll
          for (int r = 0; r < 4; ++r)
            pf[qi][jj * 4 + r] = (bf16_t)__builtin_amdgcn_exp2f(st[r]);
        }
      }
      // ---- l += 1^T . P^T  (K=32, MFMA pipe) ----
      Lacc[0] = mfma32(ones8, pf[0], Lacc[0]);
      Lacc[1] = mfma32(ones8, pf[1], Lacc[1]);
      // ---- O^T += V^T . P^T  (K=32, V in permuted-stored order) ----
#pragma unroll
      for (int dt = 0; dt < 4; ++dt) {
        bf16x8 av = *(const bf16x8*)(Vbase + vg[gi] + dt * 2048);
        O[0][dt] = mfma32(av, pf[0], O[0][dt]);
        O[1][dt] = mfma32(av, pf[1], O[1][dt]);
      }
    }
  };

  stage(0, 0);
  __syncthreads();   // tile0 drained
  stage(1, 1);       // in flight under compute(0)
  compute(0, 0);
  for (int kt = 1; kt < 31; kt += 2) {
    __syncthreads();               // drains stage of buf1(kt); all waves done with buf0
    stage(0, kt + 1);
    compute(16384, kt);
    __syncthreads();               // drains stage of buf0(kt+1); all done with buf1
    stage(1, kt + 2);
    compute(0, kt + 1);
  }
  __syncthreads();
  compute(16384, 31);

  // ---- epilogue: inv from MFMA row-sum (no shuffles) ----
#pragma unroll
  for (int qi = 0; qi < 2; ++qi) {
    float inv = 1.0f / Lacc[qi][0];
    int srow = s0 + w * 32 + qi * 16 + lr;
    float* op = out + ((size_t)b * SS + srow) * HH + h * HD;
#pragma unroll
    for (int dt = 0; dt < 4; ++dt) {
      f32x4 o = O[qi][dt];
      o *= inv;
      *(f32x4*)(op + dt * 16 + lq * 4) = o;
    }
  }
}

// ============ launcher ============
extern "C" void kernel_launch(void* const* d_in, const int* in_sizes, int n_in,
                              void* d_out, int out_size, void* d_ws, size_t ws_size,
                              hipStream_t stream) {
  const float* X    = (const float*)d_in[0];
  const float* mask = (const float*)d_in[1];
  const float* Wq   = (const float*)d_in[2];
  const float* bq   = (const float*)d_in[3];
  const float* Wk   = (const float*)d_in[4];
  const float* bk   = (const float*)d_in[5];
  const float* Wv   = (const float*)d_in[6];
  const float* bv   = (const float*)d_in[7];
  float* out = (float*)d_out;

  char* ws = (char*)d_ws;
  bf16_t* Xb = (bf16_t*)(ws);                        // 25165824 B
  bf16_t* Wb = (bf16_t*)(ws + 25165824);             //  3538944 B
  bf16_t* Qb = (bf16_t*)(ws + 28704768);             // 25165824 B
  bf16_t* Kb = (bf16_t*)(ws + 53870592);             // 25165824 B
  bf16_t* VT = (bf16_t*)(ws + 79036416);             // 25165824 B

  cvt_kernel<<<14016, 256, 0, stream>>>(X, Wq, Wk, Wv, Xb, Wb);
  qkv_gemm<<<2304, 256, 0, stream>>>(Xb, Wb, bq, bk, bv, Qb, Kb, VT);
  flash_kernel<<<1536, 256, 0, stream>>>(Qb, Kb, VT, mask, out);
}